// Round 7
// baseline (328.742 us; speedup 1.0000x reference)
//
#include <hip/hip_runtime.h>
#include <hip/hip_bf16.h>
#include <type_traits>
#include <cstdint>
#include <cstddef>

typedef __bf16 bf16_t;
typedef __attribute__((ext_vector_type(8))) __bf16 bf16x8;
typedef __attribute__((ext_vector_type(4))) float f32x4;

#define KK 8
#define BENT 4096
#define MDIM 4096
#define HIN 512
#define HENC 256
#define HCORE 512
#define HCTX 256
#define HSTATE 512
#define NPAIR (BENT*(KK-1))   // 28672

// ---------------- activation ----------------
template<int ACT>
__device__ __forceinline__ float act_f(float v) {
  if constexpr (ACT == 1) return v > 0.f ? v : expm1f(v);        // ELU
  else if constexpr (ACT == 2) return v > 0.f ? v : 0.f;         // ReLU
  else if constexpr (ACT == 3) return 1.f / (1.f + __expf(-v));  // sigmoid
  else return v;
}

// ---------------- async global->LDS (16B per lane) ----------------
__device__ __forceinline__ void gl_lds16(const bf16_t* g, bf16_t* l) {
  __builtin_amdgcn_global_load_lds(
      (const __attribute__((address_space(1))) void*)g,
      (__attribute__((address_space(3))) void*)l, 16, 0, 0);
}

// ---------------- batched transpose+convert: fp32 [R,C] -> bf16 [C,R] ----------------
struct TTasks {
  const float* src[7];
  bf16_t*      dst[7];
  int R[7], C[7], bstart[7];
};

__global__ __launch_bounds__(256)
void transpose_all_k(TTasks T) {
  __shared__ float tile[32][33];
  const int bid = blockIdx.x;
  int t = 0;
  #pragma unroll
  for (int q = 1; q < 7; ++q) if (bid >= T.bstart[q]) t = q;
  const float* __restrict__ src = T.src[t];
  bf16_t* __restrict__ dst = T.dst[t];
  const int R = T.R[t], C = T.C[t];
  const int lb = bid - T.bstart[t];
  const int gxt = C >> 5;
  const int c0 = (lb % gxt) * 32, r0 = (lb / gxt) * 32;
  const int tx = threadIdx.x, ty = threadIdx.y;
  #pragma unroll
  for (int i = 0; i < 4; ++i)
    tile[ty + 8*i][tx] = src[(size_t)(r0 + ty + 8*i) * C + c0 + tx];
  __syncthreads();
  #pragma unroll
  for (int i = 0; i < 4; ++i)
    dst[(size_t)(c0 + ty + 8*i) * R + r0 + tx] = (bf16_t)tile[tx][ty + 8*i];
}

// ---------------- fp32x8 -> bf16x8 ----------------
__device__ __forceinline__ bf16x8 cvt8(const float4& a, const float4& b) {
  bf16x8 r;
  r[0] = (bf16_t)a.x; r[1] = (bf16_t)a.y; r[2] = (bf16_t)a.z; r[3] = (bf16_t)a.w;
  r[4] = (bf16_t)b.x; r[5] = (bf16_t)b.y; r[6] = (bf16_t)b.z; r[7] = (bf16_t)b.w;
  return r;
}

// ---------------- prefetch register tile ----------------
template<typename AT> struct PF;
template<> struct PF<__bf16> { bf16x8 v; };
template<> struct PF<float>  { float4 a, b; };

// ---------------- reg-staged MFMA GEMM (XOR-swizzled LDS) — fp32-A path --------
template<int WM, int WN, int ACT, int OUTF, typename AT>
__global__ __launch_bounds__(256)
void gemm_t(const AT* __restrict__ A, const bf16_t* __restrict__ Bt,
            const float* __restrict__ bias, bf16_t* __restrict__ Cb,
            float* __restrict__ Cf, int Kd, int lda, int ldb,
            int ldc, int ldcf, int gx, int npt, int ksl, size_t pstride) {
  constexpr int TM = 32 * WM, TN = 32 * WN;
  constexpr bool A_BF16 = std::is_same<AT, __bf16>::value;
  const int tid  = threadIdx.x;
  const int lane = tid & 63;
  const int wave = tid >> 6;
  const int wm = wave >> 1, wn = wave & 1;
  const int quad = lane >> 4;
  const int l16  = lane & 15;

  const int nblk = gridDim.x;
  const int chunk = nblk >> 3;
  int tile = ((chunk << 3) == nblk) ? ((blockIdx.x & 7) * chunk + (blockIdx.x >> 3))
                                    : blockIdx.x;
  const int slice = tile / npt; tile -= slice * npt;
  const int bm0 = (tile / gx) * TM;
  const int bn0 = (tile % gx) * TN;
  A  += (size_t)slice * ksl;
  Bt += (size_t)slice * ksl;
  if (Cb) Cb += slice * pstride;
  if (Cf) Cf += slice * pstride;

  __shared__ __align__(16) bf16_t Alds[TM * 64];
  __shared__ __align__(16) bf16_t Blds[TN * 64];

  f32x4 acc[WM][WN];
  #pragma unroll
  for (int i = 0; i < WM; ++i)
    #pragma unroll
    for (int j = 0; j < WN; ++j)
      acc[i][j] = f32x4{0.f, 0.f, 0.f, 0.f};

  PF<AT> pa[TM/32];
  bf16x8 pb[TN/32];

  auto fetch = [&](int k0) {
    #pragma unroll
    for (int p = 0; p < TM/32; ++p) {
      const int f = p*256 + tid;
      const int row = f >> 3;
      const int cs = (f & 7) ^ (row & 7);
      const AT* g = A + (size_t)(bm0 + row) * lda + k0 + cs*8;
      if constexpr (A_BF16) pa[p].v = *(const bf16x8*)g;
      else { pa[p].a = ((const float4*)g)[0]; pa[p].b = ((const float4*)g)[1]; }
    }
    #pragma unroll
    for (int p = 0; p < TN/32; ++p) {
      const int f = p*256 + tid;
      const int row = f >> 3;
      const int cs = (f & 7) ^ (row & 7);
      pb[p] = *(const bf16x8*)(Bt + (size_t)(bn0 + row) * ldb + k0 + cs*8);
    }
  };

  fetch(0);
  for (int k0 = 0; k0 < Kd; k0 += 64) {
    #pragma unroll
    for (int p = 0; p < TM/32; ++p) {
      const int f = p*256 + tid;
      if constexpr (A_BF16) *(bf16x8*)((char*)Alds + (size_t)f*16) = pa[p].v;
      else                  *(bf16x8*)((char*)Alds + (size_t)f*16) = cvt8(pa[p].a, pa[p].b);
    }
    #pragma unroll
    for (int p = 0; p < TN/32; ++p) {
      const int f = p*256 + tid;
      *(bf16x8*)((char*)Blds + (size_t)f*16) = pb[p];
    }
    __syncthreads();
    if (k0 + 64 < Kd) fetch(k0 + 64);
    #pragma unroll
    for (int ks = 0; ks < 2; ++ks) {
      bf16x8 af[WM], bfr[WN];
      const int xr = l16 & 7;
      #pragma unroll
      for (int mt = 0; mt < WM; ++mt) {
        const int row = wm*16*WM + mt*16 + l16;
        af[mt] = *(const bf16x8*)&Alds[row*64 + (((ks*4 + quad) ^ xr) * 8)];
      }
      #pragma unroll
      for (int nt = 0; nt < WN; ++nt) {
        const int row = wn*16*WN + nt*16 + l16;
        bfr[nt] = *(const bf16x8*)&Blds[row*64 + (((ks*4 + quad) ^ xr) * 8)];
      }
      #pragma unroll
      for (int mt = 0; mt < WM; ++mt)
        #pragma unroll
        for (int nt = 0; nt < WN; ++nt)
          acc[mt][nt] = __builtin_amdgcn_mfma_f32_16x16x32_bf16(af[mt], bfr[nt], acc[mt][nt], 0, 0, 0);
    }
    __syncthreads();
  }

  #pragma unroll
  for (int mt = 0; mt < WM; ++mt)
    #pragma unroll
    for (int nt = 0; nt < WN; ++nt) {
      const int gcol = bn0 + wn*16*WN + nt*16 + l16;
      const float bv = bias ? bias[gcol] : 0.f;
      #pragma unroll
      for (int r = 0; r < 4; ++r) {
        const int grow = bm0 + wm*16*WM + mt*16 + quad*4 + r;
        float v = acc[mt][nt][r] + bv;
        v = act_f<ACT>(v);
        if constexpr (OUTF & 1) Cb[(size_t)grow * ldc  + gcol] = (bf16_t)v;
        if constexpr (OUTF & 2) Cf[(size_t)grow * ldcf + gcol] = v;
      }
    }
}

// ---------------- global_load_lds MFMA GEMM — disjoint dbuf + T2 swizzle --------
// (verified R6: bank-conflict-free reads + genuine cross-phase load flight)
template<int WM, int WN, int ACT, int OUTF>
__global__ __launch_bounds__(256)
void gemm_g(const bf16_t* __restrict__ A, const bf16_t* __restrict__ Bt,
            const float* __restrict__ bias, bf16_t* __restrict__ Cb,
            float* __restrict__ Cf, int Kd, int lda, int ldb,
            int ldc, int ldcf, int gx, int npt, int ksl, size_t pstride) {
  constexpr int TM = 32 * WM, TN = 32 * WN;
  const int tid  = threadIdx.x;
  const int lane = tid & 63;
  const int wave = tid >> 6;
  const int wm = wave >> 1, wn = wave & 1;
  const int quad = lane >> 4;
  const int l16  = lane & 15;

  const int nblk = gridDim.x;
  const int chunk = nblk >> 3;
  int tile = ((chunk << 3) == nblk) ? ((blockIdx.x & 7) * chunk + (blockIdx.x >> 3))
                                    : blockIdx.x;
  const int slice = tile / npt; tile -= slice * npt;
  const int bm0 = (tile / gx) * TM;
  const int bn0 = (tile % gx) * TN;
  A  += (size_t)slice * ksl;
  Bt += (size_t)slice * ksl;
  if (Cb) Cb += slice * pstride;
  if (Cf) Cf += slice * pstride;

  __shared__ __align__(16) bf16_t A0[TM * 64];
  __shared__ __align__(16) bf16_t B0[TN * 64];
  __shared__ __align__(16) bf16_t A1[TM * 64];
  __shared__ __align__(16) bf16_t B1[TN * 64];

  f32x4 acc[WM][WN];
  #pragma unroll
  for (int i = 0; i < WM; ++i)
    #pragma unroll
    for (int j = 0; j < WN; ++j)
      acc[i][j] = f32x4{0.f, 0.f, 0.f, 0.f};

  auto stage = [&](int k0, bf16_t* Ad, bf16_t* Bd) {
    #pragma unroll
    for (int p = 0; p < TM/32; ++p) {
      const int f = p*256 + tid;
      const int row = f >> 3;
      const int cs = (f & 7) ^ (row & 7);          // pre-swizzled source
      gl_lds16(A + (size_t)(bm0 + row) * lda + k0 + cs*8, Ad + (size_t)f*8);
    }
    #pragma unroll
    for (int p = 0; p < TN/32; ++p) {
      const int f = p*256 + tid;
      const int row = f >> 3;
      const int cs = (f & 7) ^ (row & 7);
      gl_lds16(Bt + (size_t)(bn0 + row) * ldb + k0 + cs*8, Bd + (size_t)f*8);
    }
  };

  auto compute = [&](const bf16_t* As, const bf16_t* Bs) {
    const int xr = l16 & 7;
    #pragma unroll
    for (int ks = 0; ks < 2; ++ks) {
      bf16x8 af[WM], bfr[WN];
      #pragma unroll
      for (int mt = 0; mt < WM; ++mt) {
        const int row = wm*16*WM + mt*16 + l16;
        af[mt] = *(const bf16x8*)&As[row*64 + (((ks*4 + quad) ^ xr) * 8)];
      }
      #pragma unroll
      for (int nt2 = 0; nt2 < WN; ++nt2) {
        const int row = wn*16*WN + nt2*16 + l16;
        bfr[nt2] = *(const bf16x8*)&Bs[row*64 + (((ks*4 + quad) ^ xr) * 8)];
      }
      #pragma unroll
      for (int mt = 0; mt < WM; ++mt)
        #pragma unroll
        for (int nt2 = 0; nt2 < WN; ++nt2)
          acc[mt][nt2] = __builtin_amdgcn_mfma_f32_16x16x32_bf16(af[mt], bfr[nt2], acc[mt][nt2], 0, 0, 0);
    }
  };

  const int nt = Kd >> 6;     // even at every call site
  stage(0, A0, B0);
  __syncthreads();
  for (int t = 0; t < nt; t += 2) {
    if (t + 1 < nt) stage((t + 1) << 6, A1, B1);
    compute(A0, B0);
    __syncthreads();
    if (t + 2 < nt) stage((t + 2) << 6, A0, B0);
    if (t + 1 < nt) {
      compute(A1, B1);
      __syncthreads();
    }
  }

  #pragma unroll
  for (int mt = 0; mt < WM; ++mt)
    #pragma unroll
    for (int nt2 = 0; nt2 < WN; ++nt2) {
      const int gcol = bn0 + wn*16*WN + nt2*16 + l16;
      const float bv = bias ? bias[gcol] : 0.f;
      #pragma unroll
      for (int r = 0; r < 4; ++r) {
        const int grow = bm0 + wm*16*WM + mt*16 + quad*4 + r;
        float v = acc[mt][nt2][r] + bv;
        v = act_f<ACT>(v);
        if constexpr (OUTF & 1) Cb[(size_t)grow * ldc  + gcol] = (bf16_t)v;
        if constexpr (OUTF & 2) Cf[(size_t)grow * ldcf + gcol] = v;
      }
    }
}

// ---------------- hybrid GEMM: fp32-A reg-staged + bf16-B gl_lds dbuf ----------
// Removes the separate fp32->bf16 convert pass for GEMM1. A-path = gemm_t's
// verified reg-prefetch + cvt-at-commit (ds_write, conflict-free, swizzled);
// B-path = gemm_g's verified gl_lds + static-disjoint dbuf + pre-swizzled src.
// Schedule per buffer pair (hazards all covered by the two __syncthreads):
//   commitA(A0) ; bar ; {fetchA(t+1), stageB(t+1->B1)} ; compute(A0,B0) ;
//   commitA(A1) ; bar ; {fetchA(t+2), stageB(t+2->B0)} ; compute(A1,B1)
template<int WM, int WN, int ACT, int OUTF>
__global__ __launch_bounds__(256)
void gemm_h(const float* __restrict__ A, const bf16_t* __restrict__ Bt,
            const float* __restrict__ bias, bf16_t* __restrict__ Cb,
            float* __restrict__ Cf, int Kd, int lda, int ldb,
            int ldc, int ldcf, int gx, int npt, int ksl, size_t pstride) {
  constexpr int TM = 32 * WM, TN = 32 * WN;
  const int tid  = threadIdx.x;
  const int lane = tid & 63;
  const int wave = tid >> 6;
  const int wm = wave >> 1, wn = wave & 1;
  const int quad = lane >> 4;
  const int l16  = lane & 15;

  const int nblk = gridDim.x;
  const int chunk = nblk >> 3;
  int tile = ((chunk << 3) == nblk) ? ((blockIdx.x & 7) * chunk + (blockIdx.x >> 3))
                                    : blockIdx.x;
  const int slice = tile / npt; tile -= slice * npt;
  const int bm0 = (tile / gx) * TM;
  const int bn0 = (tile % gx) * TN;
  A  += (size_t)slice * ksl;
  Bt += (size_t)slice * ksl;
  if (Cb) Cb += slice * pstride;
  if (Cf) Cf += slice * pstride;

  __shared__ __align__(16) bf16_t A0[TM * 64];
  __shared__ __align__(16) bf16_t B0[TN * 64];
  __shared__ __align__(16) bf16_t A1[TM * 64];
  __shared__ __align__(16) bf16_t B1[TN * 64];

  f32x4 acc[WM][WN];
  #pragma unroll
  for (int i = 0; i < WM; ++i)
    #pragma unroll
    for (int j = 0; j < WN; ++j)
      acc[i][j] = f32x4{0.f, 0.f, 0.f, 0.f};

  float4 pa[TM/32][2];

  auto fetchA = [&](int k0) {
    #pragma unroll
    for (int p = 0; p < TM/32; ++p) {
      const int f = p*256 + tid;
      const int row = f >> 3;
      const int cs = (f & 7) ^ (row & 7);
      const float* g = A + (size_t)(bm0 + row) * lda + k0 + cs*8;
      pa[p][0] = ((const float4*)g)[0];
      pa[p][1] = ((const float4*)g)[1];
    }
  };
  auto commitA = [&](bf16_t* Ad) {
    #pragma unroll
    for (int p = 0; p < TM/32; ++p) {
      const int f = p*256 + tid;
      *(bf16x8*)(Ad + (size_t)f*8) = cvt8(pa[p][0], pa[p][1]);
    }
  };
  auto stageB = [&](int k0, bf16_t* Bd) {
    #pragma unroll
    for (int p = 0; p < TN/32; ++p) {
      const int f = p*256 + tid;
      const int row = f >> 3;
      const int cs = (f & 7) ^ (row & 7);
      gl_lds16(Bt + (size_t)(bn0 + row) * ldb + k0 + cs*8, Bd + (size_t)f*8);
    }
  };
  auto compute = [&](const bf16_t* As, const bf16_t* Bs) {
    const int xr = l16 & 7;
    #pragma unroll
    for (int ks = 0; ks < 2; ++ks) {
      bf16x8 af[WM], bfr[WN];
      #pragma unroll
      for (int mt = 0; mt < WM; ++mt) {
        const int row = wm*16*WM + mt*16 + l16;
        af[mt] = *(const bf16x8*)&As[row*64 + (((ks*4 + quad) ^ xr) * 8)];
      }
      #pragma unroll
      for (int nt2 = 0; nt2 < WN; ++nt2) {
        const int row = wn*16*WN + nt2*16 + l16;
        bfr[nt2] = *(const bf16x8*)&Bs[row*64 + (((ks*4 + quad) ^ xr) * 8)];
      }
      #pragma unroll
      for (int mt = 0; mt < WM; ++mt)
        #pragma unroll
        for (int nt2 = 0; nt2 < WN; ++nt2)
          acc[mt][nt2] = __builtin_amdgcn_mfma_f32_16x16x32_bf16(af[mt], bfr[nt2], acc[mt][nt2], 0, 0, 0);
    }
  };

  const int nt = Kd >> 6;     // even (16 for GEMM1)
  fetchA(0);
  stageB(0, B0);
  for (int t = 0; t < nt; t += 2) {
    commitA(A0);              // waits pa(t) regs (compiler vmcnt), ds_write
    __syncthreads();          // A0 visible; stageB(t->B0) drained
    if (t + 1 < nt) { fetchA((t + 1) << 6); stageB((t + 1) << 6, B1); }
    compute(A0, B0);
    if (t + 1 < nt) {
      commitA(A1);            // waits pa(t+1) regs — covered by compute above
      __syncthreads();        // A1 visible; B1 drained (flew across compute)
      if (t + 2 < nt) { fetchA((t + 2) << 6); stageB((t + 2) << 6, B0); }
      compute(A1, B1);
    }
  }

  #pragma unroll
  for (int mt = 0; mt < WM; ++mt)
    #pragma unroll
    for (int nt2 = 0; nt2 < WN; ++nt2) {
      const int gcol = bn0 + wn*16*WN + nt2*16 + l16;
      const float bv = bias ? bias[gcol] : 0.f;
      #pragma unroll
      for (int r = 0; r < 4; ++r) {
        const int grow = bm0 + wm*16*WM + mt*16 + quad*4 + r;
        float v = acc[mt][nt2][r] + bv;
        v = act_f<ACT>(v);
        if constexpr (OUTF & 1) Cb[(size_t)grow * ldc  + gcol] = (bf16_t)v;
        if constexpr (OUTF & 2) Cf[(size_t)grow * ldcf + gcol] = v;
      }
    }
}

// ---------------- split-K(4) reduce + bias + ELU -> total[:,512:] ----------------
__global__ __launch_bounds__(256)
void reduce_elu_k(const bf16_t* __restrict__ P, const float* __restrict__ b,
                  bf16_t* __restrict__ total) {
  const int gid = blockIdx.x * 256 + threadIdx.x;   // 0..262143
  const int e = gid >> 6, c8 = (gid & 63) * 8;
  const float4 b0 = *(const float4*)(b + c8);
  const float4 b1 = *(const float4*)(b + c8 + 4);
  float s[8] = {b0.x, b0.y, b0.z, b0.w, b1.x, b1.y, b1.z, b1.w};
  #pragma unroll
  for (int sl = 0; sl < 4; ++sl) {
    bf16x8 v = *(const bf16x8*)(P + (size_t)sl*BENT*512 + (size_t)e*512 + c8);
    #pragma unroll
    for (int j = 0; j < 8; ++j) s[j] += (float)v[j];
  }
  bf16x8 o;
  #pragma unroll
  for (int j = 0; j < 8; ++j) o[j] = (bf16_t)act_f<1>(s[j]);
  *(bf16x8*)(total + (size_t)e * 1024 + 512 + c8) = o;
}

// ---------------- fused combine + attention ----------------
__global__ __launch_bounds__(256)
void combine_att_k(const float* __restrict__ UV, const float* __restrict__ bc,
                   const float* __restrict__ Watt, const float* __restrict__ batt,
                   bf16_t* __restrict__ core_out, float* __restrict__ att) {
  const int r = blockIdx.x * 4 + (threadIdx.x >> 6);   // pair row 0..28671
  const int lane = threadIdx.x & 63;
  const int e = r / 7, j = r - e * 7;
  const int i = e & 7;
  const int p = (j < i) ? j : j + 1;
  const int pent = (e & ~7) + p;
  const float4 u0 = ((const float4*)(UV + (size_t)pent * 1024))[lane*2];
  const float4 u1 = ((const float4*)(UV + (size_t)pent * 1024))[lane*2 + 1];
  const float4 v0 = ((const float4*)(UV + (size_t)e    * 1024 + 512))[lane*2];
  const float4 v1 = ((const float4*)(UV + (size_t)e    * 1024 + 512))[lane*2 + 1];
  const float4 b0 = ((const float4*)(bc))[lane*2];
  const float4 b1 = ((const float4*)(bc))[lane*2 + 1];
  const float4 w0 = ((const float4*)(Watt + lane*8))[0];
  const float4 w1 = ((const float4*)(Watt + lane*8))[1];
  float s[8];
  s[0] = u0.x+v0.x+b0.x; s[1] = u0.y+v0.y+b0.y;
  s[2] = u0.z+v0.z+b0.z; s[3] = u0.w+v0.w+b0.w;
  s[4] = u1.x+v1.x+b1.x; s[5] = u1.y+v1.y+b1.y;
  s[6] = u1.z+v1.z+b1.z; s[7] = u1.w+v1.w+b1.w;
  bf16x8 o;
  #pragma unroll
  for (int q = 0; q < 8; ++q) { s[q] = s[q] > 0.f ? s[q] : 0.f; o[q] = (bf16_t)s[q]; }
  *(bf16x8*)(core_out + (size_t)r * HCORE + lane*8) = o;
  float d = s[0]*w0.x + s[1]*w0.y + s[2]*w0.z + s[3]*w0.w
          + s[4]*w1.x + s[5]*w1.y + s[6]*w1.z + s[7]*w1.w;
  #pragma unroll
  for (int off = 32; off > 0; off >>= 1) d += __shfl_down(d, off, 64);
  if (lane == 0) att[r] = 1.f / (1.f + __expf(-(d + batt[0])));
}

// ---------------- effect sum + total concat ----------------
__global__ __launch_bounds__(256)
void effect_k(const float* __restrict__ att, const bf16_t* __restrict__ ctx,
              const bf16_t* __restrict__ state1, bf16_t* __restrict__ total) {
  const int e = blockIdx.x;     // 0..4095
  const int c = threadIdx.x;    // 0..255
  float s = 0.f;
  #pragma unroll
  for (int j = 0; j < 7; ++j)
    s += att[e * 7 + j] * (float)ctx[(size_t)(e * 7 + j) * HCTX + c];
  total[(size_t)e * 1024 + 256 + c] = (bf16_t)s;
  total[(size_t)e * 1024 + c]       = state1[(size_t)e * HENC + c];
}

extern "C" void kernel_launch(void* const* d_in, const int* in_sizes, int n_in,
                              void* d_out, int out_size, void* d_ws, size_t ws_size,
                              hipStream_t stream) {
  const float* inputs = (const float*)d_in[0];
  const float* state  = (const float*)d_in[1];
  const float* W_in   = (const float*)d_in[2];
  const float* b_in   = (const float*)d_in[3];
  const float* W_enc  = (const float*)d_in[4];
  const float* b_enc  = (const float*)d_in[5];
  const float* W_core = (const float*)d_in[6];
  const float* b_core = (const float*)d_in[7];
  const float* W_ctx  = (const float*)d_in[8];
  const float* b_ctx  = (const float*)d_in[9];
  const float* W_att  = (const float*)d_in[10];
  const float* b_att  = (const float*)d_in[11];
  const float* W_rec  = (const float*)d_in[12];
  const float* b_rec  = (const float*)d_in[13];
  const float* W_out  = (const float*)d_in[14];
  const float* b_out  = (const float*)d_in[15];

  float* out_f       = (float*)d_out;                      // [4096,4096] fp32
  float* new_state_f = out_f + (size_t)BENT * MDIM;        // [4096,512]  fp32

  char* ws = (char*)d_ws;
  auto alloc = [&](size_t bytes) {
    char* p = ws;
    ws += (bytes + 255) & ~(size_t)255;
    return p;
  };
  bf16_t* WinT    = (bf16_t*)alloc((size_t)HIN * MDIM * 2);     // [512,4096]
  bf16_t* WencT   = (bf16_t*)alloc((size_t)HENC * HSTATE * 2);  // [256,512]
  bf16_t* WcoreT2 = (bf16_t*)alloc((size_t)1024 * HENC * 2);    // [1024,256] packed
  bf16_t* WctxT   = (bf16_t*)alloc((size_t)HCTX * HCORE * 2);   // [256,512]
  bf16_t* WrecT   = (bf16_t*)alloc((size_t)HSTATE * 1024 * 2);  // [512,1024]
  bf16_t* WoutT   = (bf16_t*)alloc((size_t)MDIM * HSTATE * 2);  // [4096,512]
  bf16_t* state1  = (bf16_t*)alloc((size_t)BENT * HENC * 2);    // [4096,256]
  bf16_t* total   = (bf16_t*)alloc((size_t)BENT * 1024 * 2);    // [4096,1024]
  bf16_t* ns_b    = (bf16_t*)alloc((size_t)BENT * HSTATE * 2);  // [4096,512]
  float*  UV      = (float*)alloc((size_t)BENT * 1024 * 4);     // [4096,1024] fp32
  char*   S32     = alloc((size_t)8 * BENT * 512 * 2);          // P bf16 [4][4096][512] -> core_out
  bf16_t* P        = (bf16_t*)S32;
  bf16_t* core_out = (bf16_t*)S32;                              // [28672,512] (after P dead)
  bf16_t* context  = (bf16_t*)alloc((size_t)NPAIR * HCTX * 2);  // [28672,256]
  float*  att      = (float*)alloc((size_t)NPAIR * 4);          // [28672]

  // ---- one batched transpose kernel for all 7 weight transposes ----
  TTasks T;
  T.src[0]=W_in;              T.dst[0]=WinT;           T.R[0]=MDIM;  T.C[0]=HIN;   // 2048 blocks
  T.src[1]=W_enc;             T.dst[1]=WencT;          T.R[1]=HSTATE;T.C[1]=HENC;  // 128
  T.src[2]=W_core;            T.dst[2]=WcoreT2;        T.R[2]=256;   T.C[2]=HCORE; // 128
  T.src[3]=W_core+256*HCORE;  T.dst[3]=WcoreT2+512*256;T.R[3]=256;   T.C[3]=HCORE; // 128
  T.src[4]=W_ctx;             T.dst[4]=WctxT;          T.R[4]=HCORE; T.C[4]=HCTX;  // 128
  T.src[5]=W_rec;             T.dst[5]=WrecT;          T.R[5]=1024;  T.C[5]=HSTATE;// 512
  T.src[6]=W_out;             T.dst[6]=WoutT;          T.R[6]=HSTATE;T.C[6]=MDIM;  // 2048
  int bs = 0;
  for (int t = 0; t < 7; ++t) {
    T.bstart[t] = bs;
    bs += (T.C[t] >> 5) * (T.R[t] >> 5);
  }
  transpose_all_k<<<bs, dim3(32, 8), 0, stream>>>(T);

  // GEMM1 split-K=4, 128x128 tiles, fp32-A hybrid (no convert pass):
  // P[s] = inputs[:, s*1024:] @ W_in-slice (bf16 partials), K=1024/slice
  gemm_h<4,4,0,1><<<512, 256, 0, stream>>>(
      inputs, WinT, nullptr, P, nullptr, 1024, MDIM, MDIM, 512, 0, 4, 128, 1024, (size_t)BENT*512);
  // x = elu(sum_s P[s] + b_in) -> total[:,512:]
  reduce_elu_k<<<1024, 256, 0, stream>>>(P, b_in, total);
  // state1 = relu(state @ W_enc + b_enc)  [4096x256, K=512] tile 64x64 (fp32-A path)
  gemm_t<2,2,2,1,float><<<256, 256, 0, stream>>>(
      state, WencT, b_enc, state1, nullptr, HSTATE, HSTATE, HSTATE, HENC, 0, 4, 256, 0, 0);
  // UV = state1 @ [Wc_partner | Wc_self]  [4096x1024, K=256] tile 64x128
  gemm_g<2,4,0,2><<<512, 256, 0, stream>>>(
      state1, WcoreT2, nullptr, nullptr, UV, HENC, HENC, HENC, 0, 1024, 8, 512, 0, 0);
  // core_out = relu(UV[partner] + UV[self] + b_core); att fused   (P dead now)
  combine_att_k<<<NPAIR/4, 256, 0, stream>>>(UV, b_core, W_att, b_att, core_out, att);
  // context = relu(core_out @ W_ctx + b_ctx)  [28672x256, K=512] tile 128x64
  gemm_g<4,2,2,1><<<896, 256, 0, stream>>>(
      core_out, WctxT, b_ctx, context, nullptr, HCORE, HCORE, HCORE, HCTX, 0, 4, 896, 0, 0);
  // effect sum + concat into total[:, 0:512]
  effect_k<<<BENT, 256, 0, stream>>>(att, context, state1, total);
  // new_state = sigmoid(total @ W_rec + b_rec)  [4096x512, K=1024] tile 64x64
  gemm_g<2,2,3,3><<<512, 256, 0, stream>>>(
      total, WrecT, b_rec, ns_b, new_state_f, 1024, 1024, 1024, HSTATE, HSTATE, 8, 512, 0, 0);
  // out = sigmoid(new_state @ W_out + b_out)  [4096x4096, K=512] tile 128x128
  gemm_g<4,4,3,2><<<1024, 256, 0, stream>>>(
      ns_b, WoutT, b_out, nullptr, out_f, HSTATE, HSTATE, HSTATE, 0, MDIM, 32, 1024, 0, 0);
}

// Round 8
// 306.805 us; speedup vs baseline: 1.0715x; 1.0715x over previous
//
#include <hip/hip_runtime.h>
#include <hip/hip_bf16.h>
#include <type_traits>
#include <cstdint>
#include <cstddef>

typedef __bf16 bf16_t;
typedef __attribute__((ext_vector_type(8))) __bf16 bf16x8;
typedef __attribute__((ext_vector_type(4))) float f32x4;

#define KK 8
#define BENT 4096
#define MDIM 4096
#define HIN 512
#define HENC 256
#define HCORE 512
#define HCTX 256
#define HSTATE 512
#define NPAIR (BENT*(KK-1))   // 28672

// ---------------- activation ----------------
template<int ACT>
__device__ __forceinline__ float act_f(float v) {
  if constexpr (ACT == 1) return v > 0.f ? v : expm1f(v);        // ELU
  else if constexpr (ACT == 2) return v > 0.f ? v : 0.f;         // ReLU
  else if constexpr (ACT == 3) return 1.f / (1.f + __expf(-v));  // sigmoid
  else return v;
}

// ---------------- async global->LDS (16B per lane) ----------------
__device__ __forceinline__ void gl_lds16(const bf16_t* g, bf16_t* l) {
  __builtin_amdgcn_global_load_lds(
      (const __attribute__((address_space(1))) void*)g,
      (__attribute__((address_space(3))) void*)l, 16, 0, 0);
}

// ---------------- batched transpose+convert: fp32 [R,C] -> bf16 [C,R] ----------------
struct TTasks {
  const float* src[7];
  bf16_t*      dst[7];
  int R[7], C[7], bstart[7];
};

__global__ __launch_bounds__(256)
void transpose_all_k(TTasks T) {
  __shared__ float tile[32][33];
  const int bid = blockIdx.x;
  int t = 0;
  #pragma unroll
  for (int q = 1; q < 7; ++q) if (bid >= T.bstart[q]) t = q;
  const float* __restrict__ src = T.src[t];
  bf16_t* __restrict__ dst = T.dst[t];
  const int R = T.R[t], C = T.C[t];
  const int lb = bid - T.bstart[t];
  const int gxt = C >> 5;
  const int c0 = (lb % gxt) * 32, r0 = (lb / gxt) * 32;
  const int tx = threadIdx.x, ty = threadIdx.y;
  #pragma unroll
  for (int i = 0; i < 4; ++i)
    tile[ty + 8*i][tx] = src[(size_t)(r0 + ty + 8*i) * C + c0 + tx];
  __syncthreads();
  #pragma unroll
  for (int i = 0; i < 4; ++i)
    dst[(size_t)(c0 + ty + 8*i) * R + r0 + tx] = (bf16_t)tile[tx][ty + 8*i];
}

// ---------------- fp32x8 -> bf16x8 ----------------
__device__ __forceinline__ bf16x8 cvt8(const float4& a, const float4& b) {
  bf16x8 r;
  r[0] = (bf16_t)a.x; r[1] = (bf16_t)a.y; r[2] = (bf16_t)a.z; r[3] = (bf16_t)a.w;
  r[4] = (bf16_t)b.x; r[5] = (bf16_t)b.y; r[6] = (bf16_t)b.z; r[7] = (bf16_t)b.w;
  return r;
}

__global__ __launch_bounds__(256)
void convert_k(const float* __restrict__ src, bf16_t* __restrict__ dst) {
  const size_t gid = (size_t)blockIdx.x * 256 + threadIdx.x;   // one bf16x8 each
  const float4 a = ((const float4*)src)[gid * 2];
  const float4 b = ((const float4*)src)[gid * 2 + 1];
  ((bf16x8*)dst)[gid] = cvt8(a, b);
}

// ---------------- prefetch register tile ----------------
template<typename AT> struct PF;
template<> struct PF<__bf16> { bf16x8 v; };
template<> struct PF<float>  { float4 a, b; };

// ---------------- reg-staged MFMA GEMM (XOR-swizzled LDS) — fp32-A path --------
template<int WM, int WN, int ACT, int OUTF, typename AT>
__global__ __launch_bounds__(256)
void gemm_t(const AT* __restrict__ A, const bf16_t* __restrict__ Bt,
            const float* __restrict__ bias, bf16_t* __restrict__ Cb,
            float* __restrict__ Cf, int Kd, int lda, int ldb,
            int ldc, int ldcf, int gx, int npt, int ksl, size_t pstride) {
  constexpr int TM = 32 * WM, TN = 32 * WN;
  constexpr bool A_BF16 = std::is_same<AT, __bf16>::value;
  const int tid  = threadIdx.x;
  const int lane = tid & 63;
  const int wave = tid >> 6;
  const int wm = wave >> 1, wn = wave & 1;
  const int quad = lane >> 4;
  const int l16  = lane & 15;

  const int nblk = gridDim.x;
  const int chunk = nblk >> 3;
  int tile = ((chunk << 3) == nblk) ? ((blockIdx.x & 7) * chunk + (blockIdx.x >> 3))
                                    : blockIdx.x;
  const int slice = tile / npt; tile -= slice * npt;
  const int bm0 = (tile / gx) * TM;
  const int bn0 = (tile % gx) * TN;
  A  += (size_t)slice * ksl;
  Bt += (size_t)slice * ksl;
  if (Cb) Cb += slice * pstride;
  if (Cf) Cf += slice * pstride;

  __shared__ __align__(16) bf16_t Alds[TM * 64];
  __shared__ __align__(16) bf16_t Blds[TN * 64];

  f32x4 acc[WM][WN];
  #pragma unroll
  for (int i = 0; i < WM; ++i)
    #pragma unroll
    for (int j = 0; j < WN; ++j)
      acc[i][j] = f32x4{0.f, 0.f, 0.f, 0.f};

  PF<AT> pa[TM/32];
  bf16x8 pb[TN/32];

  auto fetch = [&](int k0) {
    #pragma unroll
    for (int p = 0; p < TM/32; ++p) {
      const int f = p*256 + tid;
      const int row = f >> 3;
      const int cs = (f & 7) ^ (row & 7);
      const AT* g = A + (size_t)(bm0 + row) * lda + k0 + cs*8;
      if constexpr (A_BF16) pa[p].v = *(const bf16x8*)g;
      else { pa[p].a = ((const float4*)g)[0]; pa[p].b = ((const float4*)g)[1]; }
    }
    #pragma unroll
    for (int p = 0; p < TN/32; ++p) {
      const int f = p*256 + tid;
      const int row = f >> 3;
      const int cs = (f & 7) ^ (row & 7);
      pb[p] = *(const bf16x8*)(Bt + (size_t)(bn0 + row) * ldb + k0 + cs*8);
    }
  };

  fetch(0);
  for (int k0 = 0; k0 < Kd; k0 += 64) {
    #pragma unroll
    for (int p = 0; p < TM/32; ++p) {
      const int f = p*256 + tid;
      if constexpr (A_BF16) *(bf16x8*)((char*)Alds + (size_t)f*16) = pa[p].v;
      else                  *(bf16x8*)((char*)Alds + (size_t)f*16) = cvt8(pa[p].a, pa[p].b);
    }
    #pragma unroll
    for (int p = 0; p < TN/32; ++p) {
      const int f = p*256 + tid;
      *(bf16x8*)((char*)Blds + (size_t)f*16) = pb[p];
    }
    __syncthreads();
    if (k0 + 64 < Kd) fetch(k0 + 64);
    #pragma unroll
    for (int ks = 0; ks < 2; ++ks) {
      bf16x8 af[WM], bfr[WN];
      const int xr = l16 & 7;
      #pragma unroll
      for (int mt = 0; mt < WM; ++mt) {
        const int row = wm*16*WM + mt*16 + l16;
        af[mt] = *(const bf16x8*)&Alds[row*64 + (((ks*4 + quad) ^ xr) * 8)];
      }
      #pragma unroll
      for (int nt = 0; nt < WN; ++nt) {
        const int row = wn*16*WN + nt*16 + l16;
        bfr[nt] = *(const bf16x8*)&Blds[row*64 + (((ks*4 + quad) ^ xr) * 8)];
      }
      #pragma unroll
      for (int mt = 0; mt < WM; ++mt)
        #pragma unroll
        for (int nt = 0; nt < WN; ++nt)
          acc[mt][nt] = __builtin_amdgcn_mfma_f32_16x16x32_bf16(af[mt], bfr[nt], acc[mt][nt], 0, 0, 0);
    }
    __syncthreads();
  }

  #pragma unroll
  for (int mt = 0; mt < WM; ++mt)
    #pragma unroll
    for (int nt = 0; nt < WN; ++nt) {
      const int gcol = bn0 + wn*16*WN + nt*16 + l16;
      const float bv = bias ? bias[gcol] : 0.f;
      #pragma unroll
      for (int r = 0; r < 4; ++r) {
        const int grow = bm0 + wm*16*WM + mt*16 + quad*4 + r;
        float v = acc[mt][nt][r] + bv;
        v = act_f<ACT>(v);
        if constexpr (OUTF & 1) Cb[(size_t)grow * ldc  + gcol] = (bf16_t)v;
        if constexpr (OUTF & 2) Cf[(size_t)grow * ldcf + gcol] = v;
      }
    }
}

// ---------------- global_load_lds MFMA GEMM — disjoint dbuf + T2 swizzle --------
// (verified R6: bank-conflict-free reads + genuine cross-phase load flight)
template<int WM, int WN, int ACT, int OUTF>
__global__ __launch_bounds__(256)
void gemm_g(const bf16_t* __restrict__ A, const bf16_t* __restrict__ Bt,
            const float* __restrict__ bias, bf16_t* __restrict__ Cb,
            float* __restrict__ Cf, int Kd, int lda, int ldb,
            int ldc, int ldcf, int gx, int npt, int ksl, size_t pstride) {
  constexpr int TM = 32 * WM, TN = 32 * WN;
  const int tid  = threadIdx.x;
  const int lane = tid & 63;
  const int wave = tid >> 6;
  const int wm = wave >> 1, wn = wave & 1;
  const int quad = lane >> 4;
  const int l16  = lane & 15;

  const int nblk = gridDim.x;
  const int chunk = nblk >> 3;
  int tile = ((chunk << 3) == nblk) ? ((blockIdx.x & 7) * chunk + (blockIdx.x >> 3))
                                    : blockIdx.x;
  const int slice = tile / npt; tile -= slice * npt;
  const int bm0 = (tile / gx) * TM;
  const int bn0 = (tile % gx) * TN;
  A  += (size_t)slice * ksl;
  Bt += (size_t)slice * ksl;
  if (Cb) Cb += slice * pstride;
  if (Cf) Cf += slice * pstride;

  __shared__ __align__(16) bf16_t A0[TM * 64];
  __shared__ __align__(16) bf16_t B0[TN * 64];
  __shared__ __align__(16) bf16_t A1[TM * 64];
  __shared__ __align__(16) bf16_t B1[TN * 64];

  f32x4 acc[WM][WN];
  #pragma unroll
  for (int i = 0; i < WM; ++i)
    #pragma unroll
    for (int j = 0; j < WN; ++j)
      acc[i][j] = f32x4{0.f, 0.f, 0.f, 0.f};

  auto stage = [&](int k0, bf16_t* Ad, bf16_t* Bd) {
    #pragma unroll
    for (int p = 0; p < TM/32; ++p) {
      const int f = p*256 + tid;
      const int row = f >> 3;
      const int cs = (f & 7) ^ (row & 7);          // pre-swizzled source
      gl_lds16(A + (size_t)(bm0 + row) * lda + k0 + cs*8, Ad + (size_t)f*8);
    }
    #pragma unroll
    for (int p = 0; p < TN/32; ++p) {
      const int f = p*256 + tid;
      const int row = f >> 3;
      const int cs = (f & 7) ^ (row & 7);
      gl_lds16(Bt + (size_t)(bn0 + row) * ldb + k0 + cs*8, Bd + (size_t)f*8);
    }
  };

  auto compute = [&](const bf16_t* As, const bf16_t* Bs) {
    const int xr = l16 & 7;
    #pragma unroll
    for (int ks = 0; ks < 2; ++ks) {
      bf16x8 af[WM], bfr[WN];
      #pragma unroll
      for (int mt = 0; mt < WM; ++mt) {
        const int row = wm*16*WM + mt*16 + l16;
        af[mt] = *(const bf16x8*)&As[row*64 + (((ks*4 + quad) ^ xr) * 8)];
      }
      #pragma unroll
      for (int nt2 = 0; nt2 < WN; ++nt2) {
        const int row = wn*16*WN + nt2*16 + l16;
        bfr[nt2] = *(const bf16x8*)&Bs[row*64 + (((ks*4 + quad) ^ xr) * 8)];
      }
      #pragma unroll
      for (int mt = 0; mt < WM; ++mt)
        #pragma unroll
        for (int nt2 = 0; nt2 < WN; ++nt2)
          acc[mt][nt2] = __builtin_amdgcn_mfma_f32_16x16x32_bf16(af[mt], bfr[nt2], acc[mt][nt2], 0, 0, 0);
    }
  };

  const int nt = Kd >> 6;     // even at every call site
  stage(0, A0, B0);
  __syncthreads();
  for (int t = 0; t < nt; t += 2) {
    if (t + 1 < nt) stage((t + 1) << 6, A1, B1);
    compute(A0, B0);
    __syncthreads();
    if (t + 2 < nt) stage((t + 2) << 6, A0, B0);
    if (t + 1 < nt) {
      compute(A1, B1);
      __syncthreads();
    }
  }

  #pragma unroll
  for (int mt = 0; mt < WM; ++mt)
    #pragma unroll
    for (int nt2 = 0; nt2 < WN; ++nt2) {
      const int gcol = bn0 + wn*16*WN + nt2*16 + l16;
      const float bv = bias ? bias[gcol] : 0.f;
      #pragma unroll
      for (int r = 0; r < 4; ++r) {
        const int grow = bm0 + wm*16*WM + mt*16 + quad*4 + r;
        float v = acc[mt][nt2][r] + bv;
        v = act_f<ACT>(v);
        if constexpr (OUTF & 1) Cb[(size_t)grow * ldc  + gcol] = (bf16_t)v;
        if constexpr (OUTF & 2) Cf[(size_t)grow * ldcf + gcol] = v;
      }
    }
}

// ---------------- split-K(8) reduce + bias + ELU -> total[:,512:] ----------------
__global__ __launch_bounds__(256)
void reduce_elu_k(const bf16_t* __restrict__ P, const float* __restrict__ b,
                  bf16_t* __restrict__ total) {
  const int gid = blockIdx.x * 256 + threadIdx.x;   // 0..262143
  const int e = gid >> 6, c8 = (gid & 63) * 8;
  const float4 b0 = *(const float4*)(b + c8);
  const float4 b1 = *(const float4*)(b + c8 + 4);
  float s[8] = {b0.x, b0.y, b0.z, b0.w, b1.x, b1.y, b1.z, b1.w};
  #pragma unroll
  for (int sl = 0; sl < 8; ++sl) {
    bf16x8 v = *(const bf16x8*)(P + (size_t)sl*BENT*512 + (size_t)e*512 + c8);
    #pragma unroll
    for (int j = 0; j < 8; ++j) s[j] += (float)v[j];
  }
  bf16x8 o;
  #pragma unroll
  for (int j = 0; j < 8; ++j) o[j] = (bf16_t)act_f<1>(s[j]);
  *(bf16x8*)(total + (size_t)e * 1024 + 512 + c8) = o;
}

// ---------------- fused combine + attention (UV in bf16) ----------------
__global__ __launch_bounds__(256)
void combine_att_k(const bf16_t* __restrict__ UV, const float* __restrict__ bc,
                   const float* __restrict__ Watt, const float* __restrict__ batt,
                   bf16_t* __restrict__ core_out, float* __restrict__ att) {
  const int r = blockIdx.x * 4 + (threadIdx.x >> 6);   // pair row 0..28671
  const int lane = threadIdx.x & 63;
  const int e = r / 7, j = r - e * 7;
  const int i = e & 7;
  const int p = (j < i) ? j : j + 1;
  const int pent = (e & ~7) + p;
  const bf16x8 u = *(const bf16x8*)(UV + (size_t)pent * 1024 + lane*8);
  const bf16x8 v = *(const bf16x8*)(UV + (size_t)e    * 1024 + 512 + lane*8);
  const float4 b0 = ((const float4*)(bc))[lane*2];
  const float4 b1 = ((const float4*)(bc))[lane*2 + 1];
  const float4 w0 = ((const float4*)(Watt + lane*8))[0];
  const float4 w1 = ((const float4*)(Watt + lane*8))[1];
  float s[8];
  s[0] = (float)u[0]+(float)v[0]+b0.x; s[1] = (float)u[1]+(float)v[1]+b0.y;
  s[2] = (float)u[2]+(float)v[2]+b0.z; s[3] = (float)u[3]+(float)v[3]+b0.w;
  s[4] = (float)u[4]+(float)v[4]+b1.x; s[5] = (float)u[5]+(float)v[5]+b1.y;
  s[6] = (float)u[6]+(float)v[6]+b1.z; s[7] = (float)u[7]+(float)v[7]+b1.w;
  bf16x8 o;
  #pragma unroll
  for (int q = 0; q < 8; ++q) { s[q] = s[q] > 0.f ? s[q] : 0.f; o[q] = (bf16_t)s[q]; }
  *(bf16x8*)(core_out + (size_t)r * HCORE + lane*8) = o;
  float d = s[0]*w0.x + s[1]*w0.y + s[2]*w0.z + s[3]*w0.w
          + s[4]*w1.x + s[5]*w1.y + s[6]*w1.z + s[7]*w1.w;
  #pragma unroll
  for (int off = 32; off > 0; off >>= 1) d += __shfl_down(d, off, 64);
  if (lane == 0) att[r] = 1.f / (1.f + __expf(-(d + batt[0])));
}

// ---------------- effect sum + total concat ----------------
__global__ __launch_bounds__(256)
void effect_k(const float* __restrict__ att, const bf16_t* __restrict__ ctx,
              const bf16_t* __restrict__ state1, bf16_t* __restrict__ total) {
  const int e = blockIdx.x;     // 0..4095
  const int c = threadIdx.x;    // 0..255
  float s = 0.f;
  #pragma unroll
  for (int j = 0; j < 7; ++j)
    s += att[e * 7 + j] * (float)ctx[(size_t)(e * 7 + j) * HCTX + c];
  total[(size_t)e * 1024 + 256 + c] = (bf16_t)s;
  total[(size_t)e * 1024 + c]       = state1[(size_t)e * HENC + c];
}

extern "C" void kernel_launch(void* const* d_in, const int* in_sizes, int n_in,
                              void* d_out, int out_size, void* d_ws, size_t ws_size,
                              hipStream_t stream) {
  const float* inputs = (const float*)d_in[0];
  const float* state  = (const float*)d_in[1];
  const float* W_in   = (const float*)d_in[2];
  const float* b_in   = (const float*)d_in[3];
  const float* W_enc  = (const float*)d_in[4];
  const float* b_enc  = (const float*)d_in[5];
  const float* W_core = (const float*)d_in[6];
  const float* b_core = (const float*)d_in[7];
  const float* W_ctx  = (const float*)d_in[8];
  const float* b_ctx  = (const float*)d_in[9];
  const float* W_att  = (const float*)d_in[10];
  const float* b_att  = (const float*)d_in[11];
  const float* W_rec  = (const float*)d_in[12];
  const float* b_rec  = (const float*)d_in[13];
  const float* W_out  = (const float*)d_in[14];
  const float* b_out  = (const float*)d_in[15];

  float* out_f       = (float*)d_out;                      // [4096,4096] fp32
  float* new_state_f = out_f + (size_t)BENT * MDIM;        // [4096,512]  fp32

  char* ws = (char*)d_ws;
  auto alloc = [&](size_t bytes) {
    char* p = ws;
    ws += (bytes + 255) & ~(size_t)255;
    return p;
  };
  bf16_t* WinT    = (bf16_t*)alloc((size_t)HIN * MDIM * 2);     // [512,4096]
  bf16_t* WencT   = (bf16_t*)alloc((size_t)HENC * HSTATE * 2);  // [256,512]
  bf16_t* WcoreT2 = (bf16_t*)alloc((size_t)1024 * HENC * 2);    // [1024,256] packed
  bf16_t* WctxT   = (bf16_t*)alloc((size_t)HCTX * HCORE * 2);   // [256,512]
  bf16_t* WrecT   = (bf16_t*)alloc((size_t)HSTATE * 1024 * 2);  // [512,1024]
  bf16_t* WoutT   = (bf16_t*)alloc((size_t)MDIM * HSTATE * 2);  // [4096,512]
  bf16_t* state1  = (bf16_t*)alloc((size_t)BENT * HENC * 2);    // [4096,256]
  bf16_t* total   = (bf16_t*)alloc((size_t)BENT * 1024 * 2);    // [4096,1024]
  bf16_t* ns_b    = (bf16_t*)alloc((size_t)BENT * HSTATE * 2);  // [4096,512]
  bf16_t* UV      = (bf16_t*)alloc((size_t)BENT * 1024 * 2);    // [4096,1024] bf16
  char*   S32     = alloc((size_t)8 * BENT * 512 * 2);          // P bf16 [8][4096][512] -> core_out
  bf16_t* P        = (bf16_t*)S32;
  bf16_t* core_out = (bf16_t*)S32;                              // [28672,512] (after P dead)
  // in_bf [4096,4096] bf16 — dead after GEMM1; OVERLAID with context+att
  bf16_t* in_bf    = (bf16_t*)alloc((size_t)BENT * MDIM * 2);   // 33.5 MB
  bf16_t* context  = in_bf;                                     // [28672,256] (14.7 MB)
  float*  att      = (float*)(in_bf + (size_t)NPAIR * HCTX);    // [28672]

  // ---- one batched transpose kernel for all 7 weight transposes ----
  TTasks T;
  T.src[0]=W_in;              T.dst[0]=WinT;           T.R[0]=MDIM;  T.C[0]=HIN;   // 2048 blocks
  T.src[1]=W_enc;             T.dst[1]=WencT;          T.R[1]=HSTATE;T.C[1]=HENC;  // 128
  T.src[2]=W_core;            T.dst[2]=WcoreT2;        T.R[2]=256;   T.C[2]=HCORE; // 128
  T.src[3]=W_core+256*HCORE;  T.dst[3]=WcoreT2+512*256;T.R[3]=256;   T.C[3]=HCORE; // 128
  T.src[4]=W_ctx;             T.dst[4]=WctxT;          T.R[4]=HCORE; T.C[4]=HCTX;  // 128
  T.src[5]=W_rec;             T.dst[5]=WrecT;          T.R[5]=1024;  T.C[5]=HSTATE;// 512
  T.src[6]=W_out;             T.dst[6]=WoutT;          T.R[6]=HSTATE;T.C[6]=MDIM;  // 2048
  int bs = 0;
  for (int t = 0; t < 7; ++t) {
    T.bstart[t] = bs;
    bs += (T.C[t] >> 5) * (T.R[t] >> 5);
  }
  transpose_all_k<<<bs, dim3(32, 8), 0, stream>>>(T);

  // inputs fp32 -> bf16 (enables gload_lds path + halves GEMM1 fetch)
  convert_k<<<(BENT*(size_t)MDIM/8)/256, 256, 0, stream>>>(inputs, in_bf);

  // GEMM1 split-K=8, 128x128 tiles: P[s] = in_bf[:, s*512:] @ W_in-slice  (bf16 partials)
  gemm_g<4,4,0,1><<<1024, 256, 0, stream>>>(
      in_bf, WinT, nullptr, P, nullptr, 512, MDIM, MDIM, 512, 0, 4, 128, 512, (size_t)BENT*512);
  // x = elu(sum_s P[s] + b_in) -> total[:,512:]
  reduce_elu_k<<<1024, 256, 0, stream>>>(P, b_in, total);
  // state1 = relu(state @ W_enc + b_enc)  [4096x256, K=512] tile 64x64 (fp32-A path)
  gemm_t<2,2,2,1,float><<<256, 256, 0, stream>>>(
      state, WencT, b_enc, state1, nullptr, HSTATE, HSTATE, HSTATE, HENC, 0, 4, 256, 0, 0);
  // UV = state1 @ [Wc_partner | Wc_self]  [4096x1024, K=256] tile 64x128, bf16 out
  gemm_g<2,4,0,1><<<512, 256, 0, stream>>>(
      state1, WcoreT2, nullptr, UV, nullptr, HENC, HENC, HENC, 1024, 0, 8, 512, 0, 0);
  // core_out = relu(UV[partner] + UV[self] + b_core); att fused   (P dead now)
  combine_att_k<<<NPAIR/4, 256, 0, stream>>>(UV, b_core, W_att, b_att, core_out, att);
  // context = relu(core_out @ W_ctx + b_ctx)  [28672x256, K=512] tile 128x64  (in_bf dead now)
  gemm_g<4,2,2,1><<<896, 256, 0, stream>>>(
      core_out, WctxT, b_ctx, context, nullptr, HCORE, HCORE, HCORE, HCTX, 0, 4, 896, 0, 0);
  // effect sum + concat into total[:, 0:512]
  effect_k<<<BENT, 256, 0, stream>>>(att, context, state1, total);
  // new_state = sigmoid(total @ W_rec + b_rec)  [4096x512, K=1024] tile 64x64
  gemm_g<2,2,3,3><<<512, 256, 0, stream>>>(
      total, WrecT, b_rec, ns_b, new_state_f, 1024, 1024, 1024, HSTATE, HSTATE, 8, 512, 0, 0);
  // out = sigmoid(new_state @ W_out + b_out)  [4096x4096, K=512] tile 128x128
  gemm_g<4,4,3,2><<<1024, 256, 0, stream>>>(
      ns_b, WoutT, b_out, nullptr, out_f, HSTATE, HSTATE, HSTATE, 0, MDIM, 32, 1024, 0, 0);
}